// Round 1
// baseline (1647.798 us; speedup 1.0000x reference)
//
#include <hip/hip_runtime.h>

#define NL 6
#define EMB 384
#define NH 6
#define HSZ 64
#define TT 256
#define NTOK 4096
#define VOC 50257
#define VOCP 50304
#define FF 1536
#define QKVW 1152

typedef __attribute__((ext_vector_type(8))) short bf16x8;
typedef __attribute__((ext_vector_type(4))) float f32x4;

__device__ __forceinline__ short f2bf(float f) {
  unsigned u = __float_as_uint(f);
  u = (u + 0x7fffu + ((u >> 16) & 1u)) >> 16;
  return (short)u;
}

// ---------------- embedding ----------------
__global__ void embed_k(const int* __restrict__ idx, const float* __restrict__ tok,
                        const float* __restrict__ pos, float* __restrict__ x) {
  int row = blockIdx.x, col = threadIdx.x;
  int t = idx[row];
  x[(size_t)row * EMB + col] = tok[(size_t)t * EMB + col] + pos[(size_t)(row & 255) * EMB + col];
}

// ---------------- transpose + cast f32 -> bf16 : dst[n][k] = src[k][n] ----------------
__global__ __launch_bounds__(256) void tcast_k(const float* __restrict__ src, short* __restrict__ dst,
                                               int K, int N, long sstr, long dstr) {
  src += (size_t)blockIdx.z * sstr;
  dst += (size_t)blockIdx.z * dstr;
  __shared__ float tile[32][33];
  int lx = threadIdx.x & 31, ly = threadIdx.x >> 5;
  int k0 = blockIdx.y << 5, n0 = blockIdx.x << 5;
#pragma unroll
  for (int j = 0; j < 4; ++j) {
    int k = k0 + ly + (j << 3), n = n0 + lx;
    tile[ly + (j << 3)][lx] = (n < N) ? src[(size_t)k * N + n] : 0.f;
  }
  __syncthreads();
#pragma unroll
  for (int j = 0; j < 4; ++j) {
    int n = n0 + ly + (j << 3), k = k0 + lx;
    dst[(size_t)n * K + k] = f2bf(tile[lx][ly + (j << 3)]);
  }
}

// ---------------- layernorm (f32 in) -> bf16 out ----------------
__global__ __launch_bounds__(256) void ln_k(const float* __restrict__ x, const float* __restrict__ g,
                                            const float* __restrict__ b, short* __restrict__ out) {
  int wave = threadIdx.x >> 6, lane = threadIdx.x & 63;
  int row = (blockIdx.x << 2) + wave;
  const float* p = x + (size_t)row * EMB;
  float v[6]; float s = 0.f;
#pragma unroll
  for (int j = 0; j < 6; ++j) { v[j] = p[lane + (j << 6)]; s += v[j]; }
#pragma unroll
  for (int o = 32; o; o >>= 1) s += __shfl_xor(s, o, 64);
  float mu = s * (1.f / EMB);
  float q = 0.f;
#pragma unroll
  for (int j = 0; j < 6; ++j) { float d = v[j] - mu; q += d * d; }
#pragma unroll
  for (int o = 32; o; o >>= 1) q += __shfl_xor(q, o, 64);
  float rstd = rsqrtf(q * (1.f / EMB) + 1e-5f);
  short* op = out + (size_t)row * EMB;
#pragma unroll
  for (int j = 0; j < 6; ++j) {
    int c = lane + (j << 6);
    op[c] = f2bf((v[j] - mu) * rstd * g[c] + b[c]);
  }
}

// ---------------- V transpose: qkv -> vt[bh][d][t] (d padded to 128, pad pre-zeroed) --------
__global__ __launch_bounds__(256) void vtrans_k(const short* __restrict__ qkv, short* __restrict__ vt) {
  int bh = blockIdx.y; int b = bh / NH, h = bh % NH;
  int t0 = blockIdx.x << 6;
  __shared__ short tile[64][72];
  int tid = threadIdx.x;
#pragma unroll
  for (int pass = 0; pass < 2; ++pass) {
    int tl = pass * 32 + (tid >> 3);
    int d0 = (tid & 7) << 3;
    uint4 v = *(const uint4*)&qkv[((size_t)(b * TT + t0 + tl)) * QKVW + 2 * EMB + h * HSZ + d0];
    *(uint4*)&tile[tl][d0] = v;
  }
  __syncthreads();
  int d = tid >> 2, tc = (tid & 3) << 4;
  short* dst = &vt[((size_t)bh * 128 + d) * TT + t0 + tc];
#pragma unroll
  for (int j = 0; j < 16; ++j) dst[j] = tile[tc + j][d];
}

// ---------------- causal softmax over scores rows -> bf16 probs ----------------
__global__ __launch_bounds__(256) void sm_k(const float* __restrict__ sc, short* __restrict__ P) {
  int wave = threadIdx.x >> 6, lane = threadIdx.x & 63;
  int r = (blockIdx.x << 2) + wave;               // 0 .. 96*256-1
  const float* s = sc + ((size_t)r << 8);
  float v[4]; float m = -1e30f;
#pragma unroll
  for (int j = 0; j < 4; ++j) { v[j] = s[lane + (j << 6)]; m = fmaxf(m, v[j]); }
#pragma unroll
  for (int o = 32; o; o >>= 1) m = fmaxf(m, __shfl_xor(m, o, 64));
  float e[4]; float sum = 0.f;
#pragma unroll
  for (int j = 0; j < 4; ++j) { e[j] = __expf(v[j] - m); sum += e[j]; }
#pragma unroll
  for (int o = 32; o; o >>= 1) sum += __shfl_xor(sum, o, 64);
  float inv = 1.f / sum;
  short* o2 = P + ((size_t)r << 8);
#pragma unroll
  for (int j = 0; j < 4; ++j) o2[lane + (j << 6)] = f2bf(e[j] * inv);
}

// ---------------- generic 128x128 MFMA GEMM: C = A[M,K] * Bt[N,K]^T ----------------
#define GM_QKV 0
#define GM_SCORES 1
#define GM_ATT 2
#define GM_RESID 3
#define GM_FC1 4
#define GM_HEAD 5

template <int MODE>
__global__ __launch_bounds__(256) void gemm_k(
    const short* __restrict__ Ag, const short* __restrict__ Btg, void* Cg,
    const float* __restrict__ bias, const float* resid,
    int K, int lda, int ldb, int ldc, int nstore, float scale) {
  __shared__ short sA[128 * 40];
  __shared__ short sB[128 * 40];
  int tid = threadIdx.x;
  int bm = blockIdx.x, bn = blockIdx.y, z = blockIdx.z;
  const short* A = Ag;
  const short* Bt = Btg;
  if constexpr (MODE == GM_SCORES) {
    size_t off = (size_t)(z / NH) * (TT * QKVW) + (size_t)(z % NH) * HSZ;
    A = Ag + off;
    Bt = Btg + off + EMB;
  } else if constexpr (MODE == GM_ATT) {
    A = Ag + (size_t)z * (TT * TT);
    Bt = Btg + (size_t)z * (128 * TT);
  }
  int wave = tid >> 6, lane = tid & 63;
  int wm = wave >> 1, wn = wave & 1;
  int lr = lane & 15, kg = (lane >> 4) << 3;
  int sr = tid >> 1, scol = (tid & 1) << 4;
  const short* gA = A + (size_t)(bm * 128 + sr) * lda + scol;
  const short* gB = Bt + (size_t)(bn * 128 + sr) * ldb + scol;
  short* sAp = &sA[sr * 40 + scol];
  short* sBp = &sB[sr * 40 + scol];
  f32x4 zero = {0.f, 0.f, 0.f, 0.f};
  f32x4 acc[4][4];
#pragma unroll
  for (int i = 0; i < 4; ++i)
#pragma unroll
    for (int j = 0; j < 4; ++j) acc[i][j] = zero;

  for (int k0 = 0; k0 < K; k0 += 32) {
    uint4 a0 = *(const uint4*)(gA + k0);
    uint4 a1 = *(const uint4*)(gA + k0 + 8);
    uint4 b0 = *(const uint4*)(gB + k0);
    uint4 b1 = *(const uint4*)(gB + k0 + 8);
    __syncthreads();
    *(uint4*)sAp = a0; *(uint4*)(sAp + 8) = a1;
    *(uint4*)sBp = b0; *(uint4*)(sBp + 8) = b1;
    __syncthreads();
    bf16x8 af[4], bfr[4];
#pragma unroll
    for (int f = 0; f < 4; ++f) af[f] = *(const bf16x8*)&sA[(wm * 64 + f * 16 + lr) * 40 + kg];
#pragma unroll
    for (int f = 0; f < 4; ++f) bfr[f] = *(const bf16x8*)&sB[(wn * 64 + f * 16 + lr) * 40 + kg];
#pragma unroll
    for (int i = 0; i < 4; ++i)
#pragma unroll
      for (int j = 0; j < 4; ++j)
        acc[i][j] = __builtin_amdgcn_mfma_f32_16x16x32_bf16(af[i], bfr[j], acc[i][j], 0, 0, 0);
  }

  int row0 = bm * 128 + wm * 64 + ((lane >> 4) << 2);
  int col0 = bn * 128 + wn * 64 + lr;

  if constexpr (MODE == GM_QKV) {
    short* C = (short*)Cg;
#pragma unroll
    for (int fm = 0; fm < 4; ++fm)
#pragma unroll
      for (int fn = 0; fn < 4; ++fn) {
        int c = col0 + fn * 16;
#pragma unroll
        for (int i = 0; i < 4; ++i) {
          int r = row0 + fm * 16 + i;
          C[(size_t)r * ldc + c] = f2bf(acc[fm][fn][i]);
        }
      }
  } else if constexpr (MODE == GM_FC1) {
    short* C = (short*)Cg;
#pragma unroll
    for (int fm = 0; fm < 4; ++fm)
#pragma unroll
      for (int fn = 0; fn < 4; ++fn) {
        int c = col0 + fn * 16;
        float bv = bias[c];
#pragma unroll
        for (int i = 0; i < 4; ++i) {
          int r = row0 + fm * 16 + i;
          C[(size_t)r * ldc + c] = f2bf(fmaxf(acc[fm][fn][i] + bv, 0.f));
        }
      }
  } else if constexpr (MODE == GM_SCORES) {
    float* C = (float*)Cg + (size_t)z * (TT * TT);
#pragma unroll
    for (int fm = 0; fm < 4; ++fm)
#pragma unroll
      for (int fn = 0; fn < 4; ++fn) {
        int c = col0 + fn * 16;
#pragma unroll
        for (int i = 0; i < 4; ++i) {
          int r = row0 + fm * 16 + i;
          float v = acc[fm][fn][i] * scale;
          if (c > r) v = -1e30f;
          C[(size_t)r * TT + c] = v;
        }
      }
  } else if constexpr (MODE == GM_ATT) {
    int b = z / NH, h = z % NH;
    short* C = (short*)Cg;
#pragma unroll
    for (int fm = 0; fm < 4; ++fm)
#pragma unroll
      for (int fn = 0; fn < 4; ++fn) {
        int c = col0 + fn * 16;
        if (c < HSZ) {
#pragma unroll
          for (int i = 0; i < 4; ++i) {
            int r = row0 + fm * 16 + i;
            C[(size_t)(b * TT + r) * EMB + h * HSZ + c] = f2bf(acc[fm][fn][i]);
          }
        }
      }
  } else if constexpr (MODE == GM_RESID) {
    float* C = (float*)Cg;
    const float* R = resid;
#pragma unroll
    for (int fm = 0; fm < 4; ++fm)
#pragma unroll
      for (int fn = 0; fn < 4; ++fn) {
        int c = col0 + fn * 16;
        float bv = bias[c];
#pragma unroll
        for (int i = 0; i < 4; ++i) {
          int r = row0 + fm * 16 + i;
          size_t o = (size_t)r * ldc + c;
          C[o] = R[o] + acc[fm][fn][i] + bv;
        }
      }
  } else if constexpr (MODE == GM_HEAD) {
    float* C = (float*)Cg;
#pragma unroll
    for (int fm = 0; fm < 4; ++fm)
#pragma unroll
      for (int fn = 0; fn < 4; ++fn) {
        int c = col0 + fn * 16;
        if (c < nstore) {
          float bv = bias[c];
#pragma unroll
          for (int i = 0; i < 4; ++i) {
            int r = row0 + fm * 16 + i;
            C[(size_t)r * ldc + c] = acc[fm][fn][i] + bv;
          }
        }
      }
  }
}

// ---------------- per-row online logsumexp loss ----------------
__global__ __launch_bounds__(256) void loss_rows_k(const float* __restrict__ logits,
                                                   const int* __restrict__ tgt,
                                                   float* __restrict__ rowloss) {
  int r = blockIdx.x;
  const float* p = logits + (size_t)r * VOC;
  int tid = threadIdx.x;
  float m = -1e30f, s = 0.f;
  for (int i = tid; i < VOC; i += 256) {
    float v = p[i];
    if (v > m) { s = s * __expf(m - v) + 1.f; m = v; }
    else s += __expf(v - m);
  }
  __shared__ float sm[256], ss[256];
  sm[tid] = m; ss[tid] = s;
  __syncthreads();
  for (int o = 128; o; o >>= 1) {
    if (tid < o) {
      float m2 = sm[tid + o], s2 = ss[tid + o];
      float M = fmaxf(sm[tid], m2);
      ss[tid] = ss[tid] * __expf(sm[tid] - M) + s2 * __expf(m2 - M);
      sm[tid] = M;
    }
    __syncthreads();
  }
  if (tid == 0) rowloss[r] = sm[0] + __logf(ss[0]) - p[tgt[r]];
}

__global__ __launch_bounds__(256) void loss_final_k(const float* __restrict__ rowloss,
                                                    float* __restrict__ out) {
  __shared__ float sb[256];
  int tid = threadIdx.x;
  float s = 0.f;
  for (int i = tid; i < NTOK; i += 256) s += rowloss[i];
  sb[tid] = s;
  __syncthreads();
  for (int o = 128; o; o >>= 1) {
    if (tid < o) sb[tid] += sb[tid + o];
    __syncthreads();
  }
  if (tid == 0) out[0] = sb[0] * (1.f / NTOK);
}

extern "C" void kernel_launch(void* const* d_in, const int* in_sizes, int n_in,
                              void* d_out, int out_size, void* d_ws, size_t ws_size,
                              hipStream_t stream) {
  const int* idx = (const int*)d_in[0];
  const int* tgt = (const int*)d_in[1];
  const float* tok = (const float*)d_in[2];
  const float* pos = (const float*)d_in[3];
  const float* Wq = (const float*)d_in[4];
  const float* Wk = (const float*)d_in[5];
  const float* Wv = (const float*)d_in[6];
  const float* Wp = (const float*)d_in[7];
  const float* bp = (const float*)d_in[8];
  const float* W1 = (const float*)d_in[9];
  const float* b1 = (const float*)d_in[10];
  const float* W2 = (const float*)d_in[11];
  const float* b2 = (const float*)d_in[12];
  const float* ln1g = (const float*)d_in[13];
  const float* ln1b = (const float*)d_in[14];
  const float* ln2g = (const float*)d_in[15];
  const float* ln2b = (const float*)d_in[16];
  const float* lnfg = (const float*)d_in[17];
  const float* lnfb = (const float*)d_in[18];
  const float* Wh = (const float*)d_in[19];
  const float* bh = (const float*)d_in[20];

  char* wp = (char*)d_ws;
  auto take = [&](size_t elems, size_t esz) {
    void* r = (void*)wp;
    wp += (elems * esz + 255) & ~(size_t)255;
    return r;
  };
  short* wqkv_t = (short*)take((size_t)NL * QKVW * EMB, 2);
  short* wproj_t = (short*)take((size_t)NL * EMB * EMB, 2);
  short* w1_t = (short*)take((size_t)NL * FF * EMB, 2);
  short* w2_t = (short*)take((size_t)NL * EMB * FF, 2);
  short* whead_t = (short*)take((size_t)VOCP * EMB, 2);
  float* x = (float*)take((size_t)NTOK * EMB, 4);
  short* hb = (short*)take((size_t)NTOK * EMB, 2);
  short* qkv = (short*)take((size_t)NTOK * QKVW, 2);
  float* sc = (float*)take((size_t)96 * TT * TT, 4);
  short* Pb = (short*)take((size_t)96 * TT * TT, 2);
  short* vt = (short*)take((size_t)96 * 128 * TT, 2);
  short* att = (short*)take((size_t)NTOK * EMB, 2);
  short* f1 = (short*)take((size_t)NTOK * FF, 2);
  float* rl = (float*)take((size_t)NTOK, 4);

  const float SCALE = 0.051031036307982884f;  // 1/sqrt(E)

  // weight prep (transpose + bf16 cast)
  tcast_k<<<dim3(12, 12, NL), 256, 0, stream>>>(Wq, wqkv_t, EMB, EMB, (long)EMB * EMB, (long)QKVW * EMB);
  tcast_k<<<dim3(12, 12, NL), 256, 0, stream>>>(Wk, wqkv_t + EMB * EMB, EMB, EMB, (long)EMB * EMB, (long)QKVW * EMB);
  tcast_k<<<dim3(12, 12, NL), 256, 0, stream>>>(Wv, wqkv_t + 2 * EMB * EMB, EMB, EMB, (long)EMB * EMB, (long)QKVW * EMB);
  tcast_k<<<dim3(12, 12, NL), 256, 0, stream>>>(Wp, wproj_t, EMB, EMB, (long)EMB * EMB, (long)EMB * EMB);
  tcast_k<<<dim3(48, 12, NL), 256, 0, stream>>>(W1, w1_t, EMB, FF, (long)EMB * FF, (long)FF * EMB);
  tcast_k<<<dim3(12, 48, NL), 256, 0, stream>>>(W2, w2_t, FF, EMB, (long)FF * EMB, (long)EMB * FF);
  tcast_k<<<dim3(VOCP / 32, 12, 1), 256, 0, stream>>>(Wh, whead_t, EMB, VOC, 0, 0);

  hipMemsetAsync(vt, 0, (size_t)96 * 128 * TT * 2, stream);
  embed_k<<<NTOK, EMB, 0, stream>>>(idx, tok, pos, x);

  for (int l = 0; l < NL; ++l) {
    ln_k<<<NTOK / 4, 256, 0, stream>>>(x, ln1g + l * EMB, ln1b + l * EMB, hb);
    gemm_k<GM_QKV><<<dim3(32, 9), 256, 0, stream>>>(hb, wqkv_t + (size_t)l * QKVW * EMB, qkv,
        nullptr, nullptr, EMB, EMB, EMB, QKVW, QKVW, 0.f);
    vtrans_k<<<dim3(4, 96), 256, 0, stream>>>(qkv, vt);
    gemm_k<GM_SCORES><<<dim3(2, 2, 96), 256, 0, stream>>>(qkv, qkv, sc,
        nullptr, nullptr, HSZ, QKVW, QKVW, TT, TT, SCALE);
    sm_k<<<96 * TT / 4, 256, 0, stream>>>(sc, Pb);
    gemm_k<GM_ATT><<<dim3(2, 1, 96), 256, 0, stream>>>(Pb, vt, att,
        nullptr, nullptr, TT, TT, TT, EMB, HSZ, 0.f);
    gemm_k<GM_RESID><<<dim3(32, 3), 256, 0, stream>>>(att, wproj_t + (size_t)l * EMB * EMB, x,
        bp + l * EMB, x, EMB, EMB, EMB, EMB, EMB, 0.f);
    ln_k<<<NTOK / 4, 256, 0, stream>>>(x, ln2g + l * EMB, ln2b + l * EMB, hb);
    gemm_k<GM_FC1><<<dim3(32, 12), 256, 0, stream>>>(hb, w1_t + (size_t)l * FF * EMB, f1,
        b1 + l * FF, nullptr, EMB, EMB, EMB, FF, FF, 0.f);
    gemm_k<GM_RESID><<<dim3(32, 3), 256, 0, stream>>>(f1, w2_t + (size_t)l * EMB * FF, x,
        b2 + l * EMB, x, FF, FF, FF, EMB, EMB, 0.f);
  }

  ln_k<<<NTOK / 4, 256, 0, stream>>>(x, lnfg, lnfb, hb);
  gemm_k<GM_HEAD><<<dim3(32, VOCP / 128), 256, 0, stream>>>(hb, whead_t, (float*)d_out,
      bh, nullptr, EMB, EMB, EMB, VOC, VOC, 0.f);
  loss_rows_k<<<NTOK, 256, 0, stream>>>((const float*)d_out, tgt, rl);
  loss_final_k<<<1, 256, 0, stream>>>(rl, (float*)d_out + (size_t)NTOK * VOC);
}

// Round 2
// 1468.321 us; speedup vs baseline: 1.1222x; 1.1222x over previous
//
#include <hip/hip_runtime.h>

#define NL 6
#define EMB 384
#define NH 6
#define HSZ 64
#define TT 256
#define NTOK 4096
#define VOC 50257
#define VOCP 50304
#define FF 1536
#define QKVW 1152
#define NCH 393

typedef __attribute__((ext_vector_type(8))) short bf16x8;
typedef __attribute__((ext_vector_type(4))) float f32x4;

__device__ __forceinline__ short f2bf(float f) {
  unsigned u = __float_as_uint(f);
  u = (u + 0x7fffu + ((u >> 16) & 1u)) >> 16;
  return (short)u;
}

// involutive 16B-granular LDS swizzle: bits[5:4] ^= f(bits[8:6]); swz(swz(x)) == x
__device__ __forceinline__ int swz16(int b) {
  return b ^ (((((b >> 6) ^ (b >> 8)) & 1) << 4) | (((b >> 7) & 1) << 5));
}

__device__ __forceinline__ void gl16(const void* g, void* l) {
  __builtin_amdgcn_global_load_lds(
      (const __attribute__((address_space(1))) unsigned*)g,
      (__attribute__((address_space(3))) unsigned*)l, 16, 0, 0);
}

// ---------------- embedding ----------------
__global__ void embed_k(const int* __restrict__ idx, const float* __restrict__ tok,
                        const float* __restrict__ pos, float* __restrict__ x) {
  int row = blockIdx.x, col = threadIdx.x;
  int t = idx[row];
  x[(size_t)row * EMB + col] = tok[(size_t)t * EMB + col] + pos[(size_t)(row & 255) * EMB + col];
}

// ---------------- transpose + cast f32 -> bf16 : dst[n][k] = src[k][n] ----------------
__global__ __launch_bounds__(256) void tcast_k(const float* __restrict__ src, short* __restrict__ dst,
                                               int K, int N, long sstr, long dstr) {
  src += (size_t)blockIdx.z * sstr;
  dst += (size_t)blockIdx.z * dstr;
  __shared__ float tile[32][33];
  int lx = threadIdx.x & 31, ly = threadIdx.x >> 5;
  int k0 = blockIdx.y << 5, n0 = blockIdx.x << 5;
#pragma unroll
  for (int j = 0; j < 4; ++j) {
    int k = k0 + ly + (j << 3), n = n0 + lx;
    tile[ly + (j << 3)][lx] = (n < N) ? src[(size_t)k * N + n] : 0.f;
  }
  __syncthreads();
#pragma unroll
  for (int j = 0; j < 4; ++j) {
    int n = n0 + ly + (j << 3), k = k0 + lx;
    dst[(size_t)n * K + k] = f2bf(tile[lx][ly + (j << 3)]);
  }
}

// ---------------- layernorm (f32 in) -> bf16 out ----------------
__global__ __launch_bounds__(256) void ln_k(const float* __restrict__ x, const float* __restrict__ g,
                                            const float* __restrict__ b, short* __restrict__ out) {
  int wave = threadIdx.x >> 6, lane = threadIdx.x & 63;
  int row = (blockIdx.x << 2) + wave;
  const float* p = x + (size_t)row * EMB;
  float v[6]; float s = 0.f;
#pragma unroll
  for (int j = 0; j < 6; ++j) { v[j] = p[lane + (j << 6)]; s += v[j]; }
#pragma unroll
  for (int o = 32; o; o >>= 1) s += __shfl_xor(s, o, 64);
  float mu = s * (1.f / EMB);
  float q = 0.f;
#pragma unroll
  for (int j = 0; j < 6; ++j) { float d = v[j] - mu; q += d * d; }
#pragma unroll
  for (int o = 32; o; o >>= 1) q += __shfl_xor(q, o, 64);
  float rstd = rsqrtf(q * (1.f / EMB) + 1e-5f);
  short* op = out + (size_t)row * EMB;
#pragma unroll
  for (int j = 0; j < 6; ++j) {
    int c = lane + (j << 6);
    op[c] = f2bf((v[j] - mu) * rstd * g[c] + b[c]);
  }
}

// ---------------- V transpose: qkv -> vt[bh][d][t] (d padded to 128, pad pre-zeroed) --------
__global__ __launch_bounds__(256) void vtrans_k(const short* __restrict__ qkv, short* __restrict__ vt) {
  int bh = blockIdx.y; int b = bh / NH, h = bh % NH;
  int t0 = blockIdx.x << 6;
  __shared__ short tile[64][72];
  int tid = threadIdx.x;
#pragma unroll
  for (int pass = 0; pass < 2; ++pass) {
    int tl = pass * 32 + (tid >> 3);
    int d0 = (tid & 7) << 3;
    uint4 v = *(const uint4*)&qkv[((size_t)(b * TT + t0 + tl)) * QKVW + 2 * EMB + h * HSZ + d0];
    *(uint4*)&tile[tl][d0] = v;
  }
  __syncthreads();
  int d = tid >> 2, tc = (tid & 3) << 4;
  short* dst = &vt[((size_t)bh * 128 + d) * TT + t0 + tc];
#pragma unroll
  for (int j = 0; j < 16; ++j) dst[j] = tile[tc + j][d];
}

// ---------------- causal softmax over scores rows -> bf16 probs ----------------
__global__ __launch_bounds__(256) void sm_k(const float* __restrict__ sc, short* __restrict__ P) {
  int wave = threadIdx.x >> 6, lane = threadIdx.x & 63;
  int r = (blockIdx.x << 2) + wave;
  const float* s = sc + ((size_t)r << 8);
  float v[4]; float m = -1e30f;
#pragma unroll
  for (int j = 0; j < 4; ++j) { v[j] = s[lane + (j << 6)]; m = fmaxf(m, v[j]); }
#pragma unroll
  for (int o = 32; o; o >>= 1) m = fmaxf(m, __shfl_xor(m, o, 64));
  float e[4]; float sum = 0.f;
#pragma unroll
  for (int j = 0; j < 4; ++j) { e[j] = __expf(v[j] - m); sum += e[j]; }
#pragma unroll
  for (int o = 32; o; o >>= 1) sum += __shfl_xor(sum, o, 64);
  float inv = 1.f / sum;
  short* o2 = P + ((size_t)r << 8);
#pragma unroll
  for (int j = 0; j < 4; ++j) o2[lane + (j << 6)] = f2bf(e[j] * inv);
}

// ---------------- generic 128x128 MFMA GEMM: C = A[M,K] * Bt[N,K]^T ----------------
#define GM_QKV 0
#define GM_SCORES 1
#define GM_ATT 2
#define GM_RESID 3
#define GM_FC1 4
#define GM_HEAD 5

template <int MODE>
__global__ __launch_bounds__(256) void gemm_k(
    const short* __restrict__ Ag, const short* __restrict__ Btg, void* Cg,
    const float* __restrict__ bias, const float* resid,
    int K, int lda, int ldb, int ldc, int nstore, float scale,
    float* __restrict__ pm, float* __restrict__ ps) {
  __shared__ alignas(1024) short sA[128 * 32];
  __shared__ alignas(1024) short sB[128 * 32];
  __shared__ float redm[2][2][64];
  __shared__ float reds[2][2][64];
  int tid = threadIdx.x;
  int bm = blockIdx.x, bn = blockIdx.y, z = blockIdx.z;
  const short* A = Ag;
  const short* Bt = Btg;
  if constexpr (MODE == GM_SCORES) {
    size_t off = (size_t)(z / NH) * (TT * QKVW) + (size_t)(z % NH) * HSZ;
    A = Ag + off;
    Bt = Btg + off + EMB;
  } else if constexpr (MODE == GM_ATT) {
    A = Ag + (size_t)z * (TT * TT);
    Bt = Btg + (size_t)z * (128 * TT);
  }
  int wave = tid >> 6, lane = tid & 63;
  int wm = wave >> 1, wn = wave & 1;
  int lr = lane & 15, kq = lane >> 4;
  size_t lda2 = (size_t)lda * 2, ldb2 = (size_t)ldb * 2;

  // staging: chunk = wave (rows wave*16..+15) and wave+4 (rows +64); per-lane src pre-swizzled
  int p = wave * 1024 + lane * 16;          // linear LDS byte pos within tile
  int q = swz16(p);                         // logical byte this LDS slot must hold
  int srow = q >> 6, scb = q & 63;
  const char* gA = (const char*)A + (size_t)(bm * 128 + srow) * lda2 + scb;
  const char* gB = (const char*)Bt + (size_t)(bn * 128 + srow) * ldb2 + scb;
  char* lA0 = (char*)sA + wave * 1024; char* lA1 = lA0 + 4096;
  char* lB0 = (char*)sB + wave * 1024; char* lB1 = lB0 + 4096;

  // fragment read addrs (loop-invariant, swizzled)
  const bf16x8* apf[4]; const bf16x8* bpf[4];
#pragma unroll
  for (int f = 0; f < 4; ++f) {
    int La = (wm * 64 + f * 16 + lr) * 64 + kq * 16;
    apf[f] = (const bf16x8*)((const char*)sA + swz16(La));
    int Lb = (wn * 64 + f * 16 + lr) * 64 + kq * 16;
    bpf[f] = (const bf16x8*)((const char*)sB + swz16(Lb));
  }

  f32x4 zero = {0.f, 0.f, 0.f, 0.f};
  f32x4 acc[4][4];
#pragma unroll
  for (int i = 0; i < 4; ++i)
#pragma unroll
    for (int j = 0; j < 4; ++j) acc[i][j] = zero;

  for (int k0 = 0; k0 < K; k0 += 32) {
    __syncthreads();
    gl16(gA, lA0); gl16(gA + 64 * lda2, lA1);
    gl16(gB, lB0); gl16(gB + 64 * ldb2, lB1);
    gA += 64; gB += 64;
    __syncthreads();
    bf16x8 af[4], bfr[4];
#pragma unroll
    for (int f = 0; f < 4; ++f) { af[f] = *apf[f]; bfr[f] = *bpf[f]; }
#pragma unroll
    for (int i = 0; i < 4; ++i)
#pragma unroll
      for (int j = 0; j < 4; ++j)
        acc[i][j] = __builtin_amdgcn_mfma_f32_16x16x32_bf16(af[i], bfr[j], acc[i][j], 0, 0, 0);
  }

  int row0 = bm * 128 + wm * 64 + (kq << 2);
  int col0 = bn * 128 + wn * 64 + lr;

  if constexpr (MODE == GM_QKV) {
    short* C = (short*)Cg;
#pragma unroll
    for (int fm = 0; fm < 4; ++fm)
#pragma unroll
      for (int fn = 0; fn < 4; ++fn) {
        int c = col0 + fn * 16;
#pragma unroll
        for (int i = 0; i < 4; ++i)
          C[(size_t)(row0 + fm * 16 + i) * ldc + c] = f2bf(acc[fm][fn][i]);
      }
  } else if constexpr (MODE == GM_FC1) {
    short* C = (short*)Cg;
#pragma unroll
    for (int fm = 0; fm < 4; ++fm)
#pragma unroll
      for (int fn = 0; fn < 4; ++fn) {
        int c = col0 + fn * 16;
        float bv = bias[c];
#pragma unroll
        for (int i = 0; i < 4; ++i)
          C[(size_t)(row0 + fm * 16 + i) * ldc + c] = f2bf(fmaxf(acc[fm][fn][i] + bv, 0.f));
      }
  } else if constexpr (MODE == GM_SCORES) {
    float* C = (float*)Cg + (size_t)z * (TT * TT);
#pragma unroll
    for (int fm = 0; fm < 4; ++fm)
#pragma unroll
      for (int fn = 0; fn < 4; ++fn) {
        int c = col0 + fn * 16;
#pragma unroll
        for (int i = 0; i < 4; ++i) {
          int r = row0 + fm * 16 + i;
          float v = acc[fm][fn][i] * scale;
          if (c > r) v = -1e30f;
          C[(size_t)r * TT + c] = v;
        }
      }
  } else if constexpr (MODE == GM_ATT) {
    int b = z / NH, h = z % NH;
    short* C = (short*)Cg;
#pragma unroll
    for (int fm = 0; fm < 4; ++fm)
#pragma unroll
      for (int fn = 0; fn < 4; ++fn) {
        int c = col0 + fn * 16;
        if (c < HSZ) {
#pragma unroll
          for (int i = 0; i < 4; ++i)
            C[(size_t)(b * TT + row0 + fm * 16 + i) * EMB + h * HSZ + c] = f2bf(acc[fm][fn][i]);
        }
      }
  } else if constexpr (MODE == GM_RESID) {
    float* C = (float*)Cg;
#pragma unroll
    for (int fm = 0; fm < 4; ++fm)
#pragma unroll
      for (int fn = 0; fn < 4; ++fn) {
        int c = col0 + fn * 16;
        float bv = bias[c];
#pragma unroll
        for (int i = 0; i < 4; ++i) {
          size_t o = (size_t)(row0 + fm * 16 + i) * ldc + c;
          C[o] = resid[o] + acc[fm][fn][i] + bv;
        }
      }
  } else if constexpr (MODE == GM_HEAD) {
    float* C = (float*)Cg;
    bool okv[4]; float bv[4];
#pragma unroll
    for (int fn = 0; fn < 4; ++fn) {
      int c = col0 + fn * 16;
      okv[fn] = c < VOC;
      bv[fn] = okv[fn] ? bias[c] : 0.f;
    }
#pragma unroll
    for (int fm = 0; fm < 4; ++fm) {
#pragma unroll
      for (int i = 0; i < 4; ++i) {
        int r = row0 + fm * 16 + i;
        float vv[4];
#pragma unroll
        for (int fn = 0; fn < 4; ++fn) {
          float v = acc[fm][fn][i] + bv[fn];
          if (okv[fn]) C[(size_t)r * VOC + col0 + fn * 16] = v;
          vv[fn] = okv[fn] ? v : -1e30f;
        }
        float mx = fmaxf(fmaxf(vv[0], vv[1]), fmaxf(vv[2], vv[3]));
        float sm = __expf(vv[0] - mx) + __expf(vv[1] - mx) + __expf(vv[2] - mx) + __expf(vv[3] - mx);
        // reduce (mx,sm) across the 16 lanes sharing this row
#pragma unroll
        for (int o = 8; o; o >>= 1) {
          float mo = __shfl_xor(mx, o, 64), so = __shfl_xor(sm, o, 64);
          float M = fmaxf(mx, mo);
          sm = sm * __expf(mx - M) + so * __expf(mo - M);
          mx = M;
        }
        if (lr == 0) {
          int rl = fm * 16 + (kq << 2) + i;
          redm[wm][wn][rl] = mx; reds[wm][wn][rl] = sm;
        }
      }
    }
    __syncthreads();
    if (tid < 128) {
      int wmm = tid >> 6, rl = tid & 63;
      float m0 = redm[wmm][0][rl], m1 = redm[wmm][1][rl];
      float s0 = reds[wmm][0][rl], s1 = reds[wmm][1][rl];
      float M = fmaxf(m0, m1);
      float S = s0 * __expf(m0 - M) + s1 * __expf(m1 - M);
      int r = bm * 128 + wmm * 64 + rl;
      pm[(size_t)r * NCH + bn] = M;
      ps[(size_t)r * NCH + bn] = S;
    }
  }
}

// ---------------- combine per-chunk LSE partials -> per-row loss ----------------
__global__ __launch_bounds__(256) void lsecomb_k(const float* __restrict__ pm, const float* __restrict__ ps,
                                                 const float* __restrict__ logits, const int* __restrict__ tgt,
                                                 float* __restrict__ rowloss) {
  int wave = threadIdx.x >> 6, lane = threadIdx.x & 63;
  int r = (blockIdx.x << 2) + wave;
  float m = -1e30f, s = 0.f;
  for (int i = lane; i < NCH; i += 64) {
    float bm = pm[(size_t)r * NCH + i], bs = ps[(size_t)r * NCH + i];
    float M = fmaxf(m, bm);
    s = s * __expf(m - M) + bs * __expf(bm - M);
    m = M;
  }
#pragma unroll
  for (int o = 32; o; o >>= 1) {
    float mo = __shfl_xor(m, o, 64), so = __shfl_xor(s, o, 64);
    float M = fmaxf(m, mo);
    s = s * __expf(m - M) + so * __expf(mo - M);
    m = M;
  }
  if (lane == 0) rowloss[r] = m + __logf(s) - logits[(size_t)r * VOC + tgt[r]];
}

__global__ __launch_bounds__(256) void loss_final_k(const float* __restrict__ rowloss,
                                                    float* __restrict__ out) {
  __shared__ float sb[256];
  int tid = threadIdx.x;
  float s = 0.f;
  for (int i = tid; i < NTOK; i += 256) s += rowloss[i];
  sb[tid] = s;
  __syncthreads();
  for (int o = 128; o; o >>= 1) {
    if (tid < o) sb[tid] += sb[tid + o];
    __syncthreads();
  }
  if (tid == 0) out[0] = sb[0] * (1.f / NTOK);
}

extern "C" void kernel_launch(void* const* d_in, const int* in_sizes, int n_in,
                              void* d_out, int out_size, void* d_ws, size_t ws_size,
                              hipStream_t stream) {
  const int* idx = (const int*)d_in[0];
  const int* tgt = (const int*)d_in[1];
  const float* tok = (const float*)d_in[2];
  const float* pos = (const float*)d_in[3];
  const float* Wq = (const float*)d_in[4];
  const float* Wk = (const float*)d_in[5];
  const float* Wv = (const float*)d_in[6];
  const float* Wp = (const float*)d_in[7];
  const float* bp = (const float*)d_in[8];
  const float* W1 = (const float*)d_in[9];
  const float* b1 = (const float*)d_in[10];
  const float* W2 = (const float*)d_in[11];
  const float* b2 = (const float*)d_in[12];
  const float* ln1g = (const float*)d_in[13];
  const float* ln1b = (const float*)d_in[14];
  const float* ln2g = (const float*)d_in[15];
  const float* ln2b = (const float*)d_in[16];
  const float* lnfg = (const float*)d_in[17];
  const float* lnfb = (const float*)d_in[18];
  const float* Wh = (const float*)d_in[19];
  const float* bh = (const float*)d_in[20];

  char* wp = (char*)d_ws;
  auto take = [&](size_t elems, size_t esz) {
    void* r = (void*)wp;
    wp += (elems * esz + 255) & ~(size_t)255;
    return r;
  };
  short* wqkv_t = (short*)take((size_t)NL * QKVW * EMB, 2);
  short* wproj_t = (short*)take((size_t)NL * EMB * EMB, 2);
  short* w1_t = (short*)take((size_t)NL * FF * EMB, 2);
  short* w2_t = (short*)take((size_t)NL * EMB * FF, 2);
  short* whead_t = (short*)take((size_t)VOCP * EMB, 2);
  float* x = (float*)take((size_t)NTOK * EMB, 4);
  short* hb = (short*)take((size_t)NTOK * EMB, 2);
  short* qkv = (short*)take((size_t)NTOK * QKVW, 2);
  float* sc = (float*)take((size_t)96 * TT * TT, 4);
  short* Pb = (short*)take((size_t)96 * TT * TT, 2);
  short* vt = (short*)take((size_t)96 * 128 * TT, 2);
  short* att = (short*)take((size_t)NTOK * EMB, 2);
  short* f1 = (short*)take((size_t)NTOK * FF, 2);
  float* rl = (float*)take((size_t)NTOK, 4);

  // LSE partials alias the (dead by then) scores buffer
  float* pm = sc;
  float* ps = sc + (size_t)NTOK * NCH;

  const float SCALE = 0.051031036307982884f;  // 1/sqrt(E)

  tcast_k<<<dim3(12, 12, NL), 256, 0, stream>>>(Wq, wqkv_t, EMB, EMB, (long)EMB * EMB, (long)QKVW * EMB);
  tcast_k<<<dim3(12, 12, NL), 256, 0, stream>>>(Wk, wqkv_t + EMB * EMB, EMB, EMB, (long)EMB * EMB, (long)QKVW * EMB);
  tcast_k<<<dim3(12, 12, NL), 256, 0, stream>>>(Wv, wqkv_t + 2 * EMB * EMB, EMB, EMB, (long)EMB * EMB, (long)QKVW * EMB);
  tcast_k<<<dim3(12, 12, NL), 256, 0, stream>>>(Wp, wproj_t, EMB, EMB, (long)EMB * EMB, (long)EMB * EMB);
  tcast_k<<<dim3(48, 12, NL), 256, 0, stream>>>(W1, w1_t, EMB, FF, (long)EMB * FF, (long)FF * EMB);
  tcast_k<<<dim3(12, 48, NL), 256, 0, stream>>>(W2, w2_t, FF, EMB, (long)FF * EMB, (long)EMB * FF);
  tcast_k<<<dim3(VOCP / 32, 12, 1), 256, 0, stream>>>(Wh, whead_t, EMB, VOC, 0, 0);

  hipMemsetAsync(vt, 0, (size_t)96 * 128 * TT * 2, stream);
  embed_k<<<NTOK, EMB, 0, stream>>>(idx, tok, pos, x);

  for (int l = 0; l < NL; ++l) {
    ln_k<<<NTOK / 4, 256, 0, stream>>>(x, ln1g + l * EMB, ln1b + l * EMB, hb);
    gemm_k<GM_QKV><<<dim3(32, 9), 256, 0, stream>>>(hb, wqkv_t + (size_t)l * QKVW * EMB, qkv,
        nullptr, nullptr, EMB, EMB, EMB, QKVW, QKVW, 0.f, nullptr, nullptr);
    vtrans_k<<<dim3(4, 96), 256, 0, stream>>>(qkv, vt);
    gemm_k<GM_SCORES><<<dim3(2, 2, 96), 256, 0, stream>>>(qkv, qkv, sc,
        nullptr, nullptr, HSZ, QKVW, QKVW, TT, TT, SCALE, nullptr, nullptr);
    sm_k<<<96 * TT / 4, 256, 0, stream>>>(sc, Pb);
    gemm_k<GM_ATT><<<dim3(2, 1, 96), 256, 0, stream>>>(Pb, vt, att,
        nullptr, nullptr, TT, TT, TT, EMB, HSZ, 0.f, nullptr, nullptr);
    gemm_k<GM_RESID><<<dim3(32, 3), 256, 0, stream>>>(att, wproj_t + (size_t)l * EMB * EMB, x,
        bp + l * EMB, x, EMB, EMB, EMB, EMB, EMB, 0.f, nullptr, nullptr);
    ln_k<<<NTOK / 4, 256, 0, stream>>>(x, ln2g + l * EMB, ln2b + l * EMB, hb);
    gemm_k<GM_FC1><<<dim3(32, 12), 256, 0, stream>>>(hb, w1_t + (size_t)l * FF * EMB, f1,
        b1 + l * FF, nullptr, EMB, EMB, EMB, FF, FF, 0.f, nullptr, nullptr);
    gemm_k<GM_RESID><<<dim3(32, 3), 256, 0, stream>>>(f1, w2_t + (size_t)l * EMB * FF, x,
        b2 + l * EMB, x, FF, FF, FF, EMB, EMB, 0.f, nullptr, nullptr);
  }

  ln_k<<<NTOK / 4, 256, 0, stream>>>(x, lnfg, lnfb, hb);
  gemm_k<GM_HEAD><<<dim3(32, NCH), 256, 0, stream>>>(hb, whead_t, (float*)d_out,
      bh, nullptr, EMB, EMB, EMB, VOC, VOC, 0.f, pm, ps);
  lsecomb_k<<<NTOK / 4, 256, 0, stream>>>(pm, ps, (const float*)d_out, tgt, rl);
  loss_final_k<<<1, 256, 0, stream>>>(rl, (float*)d_out + (size_t)NTOK * VOC);
}